// Round 6
// baseline (20.610 us; speedup 1.0000x reference)
//
#include <hip/hip_runtime.h>

#define F 26
#define A 7
#define DIM 16
#define BATCH 4096
#define TV 2083764

// ---- fully compile-time tables (constexpr => folded after unroll) ----
constexpr int OFF_[F] = {
    0, 1000000, 1500000, 1750000, 1850000, 1950000, 2000000, 2050000,
    2060000, 2070000, 2075000, 2080000, 2081000, 2082000, 2082500, 2083000,
    2083200, 2083400, 2083500, 2083600, 2083650, 2083700, 2083720, 2083740,
    2083750, 2083760};
// allowed-action bitmask per field: bit0 = full-emb, bitk = codebook action k
constexpr unsigned ALLOWED_[F] = {
    0x7E, 0x7E, 0x7E, 0x7E, 0x7E, 0x7E, 0x7E, 0x7E, 0x7E,   // f0-8
    0x3E, 0x3E,                                              // f9,10 (5000)
    0x0E, 0x0E,                                              // f11,12 (1000)
    0x06, 0x06,                                              // f13,14 (500)
    0x02, 0x02,                                              // f15,16 (200)
    0x01, 0x01, 0x01, 0x01, 0x01, 0x01, 0x01, 0x01, 0x01};  // f17-25
// live codebook-action count (prefix length of bits 1..6)
constexpr int K_[F] = {6,6,6,6,6,6,6,6,6, 5,5, 3,3, 2,2, 1,1,
                       0,0,0,0,0,0,0,0,0};
constexpr bool EMB_[F] = {false,false,false,false,false,false,false,false,
                          false,false,false,false,false,false,false,false,
                          false,true,true,true,true,true,true,true,true,true};

// Block: 256 threads = 4 waves; ONE wave per batch element.
// Lane layout: ag = lane>>4 (action group 0..3), d = lane&15 (embedding dim).
// All per-element indices (gid, codes, lin_w) are WAVE-UNIFORM -> scalar path.
__global__ __launch_bounds__(256, 4) void gsq_fm_kernel(
    const int* __restrict__ x,            // (B, F)
    const float* __restrict__ emb_table,  // (TV, 16)
    const float* __restrict__ lin_w,      // (TV, 1)
    const float* __restrict__ lin_bias,   // (1,)
    const float* __restrict__ codebooks,  // (6, F, 2048, 16)
    const int* __restrict__ assignments,  // (6, TV)
    const float* __restrict__ arch,       // (F, A)
    const float* __restrict__ gumbel,     // (F, A)
    float* __restrict__ out)              // (B,)
{
    __shared__ float probs_s[F][A];

    const int t = threadIdx.x;

    // ---- per-block probs (26 threads) ----
    if (t < F) {
        const unsigned msk = ALLOWED_[t];
        float z[A];
        float m = -1e30f;
        for (int k = 0; k < A; ++k) {
            float logit = ((msk >> k) & 1u) ? arch[t * A + k] : -1e9f;
            z[k] = logit + gumbel[t * A + k];  // TEMPERATURE == 1
            m = fmaxf(m, z[k]);
        }
        float ssum = 0.f;
        for (int k = 0; k < A; ++k) {
            z[k] = expf(z[k] - m);  // disallowed -> exactly 0.0f
            ssum += z[k];
        }
        const float inv = 1.f / ssum;
        for (int k = 0; k < A; ++k) probs_s[t][k] = z[k] * inv;
    }
    __syncthreads();

    const int lane = t & 63;
    const int wv = __builtin_amdgcn_readfirstlane(t >> 6);  // wave id, uniform
    const int b = blockIdx.x * 4 + wv;
    const int ag = lane >> 4;   // action group 0..3
    const int d  = lane & 15;   // embedding dim 0..15

    float s = 0.f;    // per-lane: sum_f xe_f[d] (replicated across ag)
    float q = 0.f;    // per-lane: sum_f xe_f[d]^2 (replicated across ag)
    float lin = 0.f;  // broadcast-accumulated scalar sum (identical all lanes)

#pragma unroll
    for (int f = 0; f < F; ++f) {
        // uniform address -> s_load; result stays in SGPRs
        const int gid = x[b * F + f] + OFF_[f];
        lin += lin_w[gid];                       // uniform -> s_load + v_add

        float xe = 0.f;
        if (EMB_[f]) {  // compile-time; only 9 tiny cached fields
            const float ev = emb_table[gid * DIM + d];   // 1 line, 4x replicated
            const float p0m = (ag == 0) ? probs_s[f][0] : 0.f;
            xe = p0m * ev;
        }

        const int K = K_[f];  // compile-time after unroll
        if (K > 0) {
            // scalar gather of the live codes (uniform s_loads, independent)
            int q0 = assignments[0 * TV + gid];
            int q1 = (K > 1) ? assignments[1 * TV + gid] : 0;
            int q2 = (K > 2) ? assignments[2 * TV + gid] : 0;
            int q3 = (K > 3) ? assignments[3 * TV + gid] : 0;
            int q4 = (K > 4) ? assignments[4 * TV + gid] : 0;
            int q5 = (K > 5) ? assignments[5 * TV + gid] : 0;

            // round 0: actions 0..3 across the 4 ag groups (one 4-row load)
            {
                const int o0 = (0 * F + f) * 2048 * DIM + q0 * DIM;
                const int o1 = (K > 1) ? (1 * F + f) * 2048 * DIM + q1 * DIM : o0;
                const int o2 = (K > 2) ? (2 * F + f) * 2048 * DIM + q2 * DIM : o0;
                const int o3 = (K > 3) ? (3 * F + f) * 2048 * DIM + q3 * DIM : o0;
                const int off = (ag & 1) ? ((ag & 2) ? o3 : o1)
                                         : ((ag & 2) ? o2 : o0);
                const float w = (ag < K) ? probs_s[f][ag + 1] : 0.f;
                xe = fmaf(w, codebooks[off + d], xe);
            }
            // round 1: actions 4..5 (only for K > 4 fields)
            if (K > 4) {
                const int o4 = (4 * F + f) * 2048 * DIM + q4 * DIM;
                const int o5 = (K > 5) ? (5 * F + f) * 2048 * DIM + q5 * DIM : o4;
                const int aa = ag + 4;
                const int off = (ag & 1) ? ((ag & 2) ? o4 : o5)
                                         : ((ag & 2) ? o4 : o4);
                const int offs = (aa == 5 && K > 5) ? o5 : o4;
                (void)off;
                const float w = (aa < K) ? probs_s[f][aa + 1] : 0.f;
                xe = fmaf(w, codebooks[offs + d], xe);
            }
        }

        // combine the 4 ag partial shares -> full xe_f[d] in every lane
        xe += __shfl_xor(xe, 16, 64);
        xe += __shfl_xor(xe, 32, 64);
        s += xe;
        q = fmaf(xe, xe, q);
    }

    // ---- reductions over the 16 dims (lane bits 0..3) ----
    float v2 = s * s;
    v2 += __shfl_xor(v2, 1, 64);
    v2 += __shfl_xor(v2, 2, 64);
    v2 += __shfl_xor(v2, 4, 64);
    v2 += __shfl_xor(v2, 8, 64);
    q += __shfl_xor(q, 1, 64);
    q += __shfl_xor(q, 2, 64);
    q += __shfl_xor(q, 4, 64);
    q += __shfl_xor(q, 8, 64);

    if (lane == 0) {
        out[b] = lin + lin_bias[0] + 0.5f * (v2 - q);
    }
}

extern "C" void kernel_launch(void* const* d_in, const int* in_sizes, int n_in,
                              void* d_out, int out_size, void* d_ws, size_t ws_size,
                              hipStream_t stream) {
    const int*   x           = (const int*)d_in[0];
    const float* emb_table   = (const float*)d_in[1];
    const float* lin_w       = (const float*)d_in[2];
    const float* lin_bias    = (const float*)d_in[3];
    const float* codebooks   = (const float*)d_in[4];
    const int*   assignments = (const int*)d_in[5];
    const float* arch        = (const float*)d_in[6];
    const float* gumbel      = (const float*)d_in[7];
    float* out = (float*)d_out;

    dim3 grid(BATCH / 4);   // 4 batch elements (1 wave each) per block
    dim3 block(256);
    hipLaunchKernelGGL(gsq_fm_kernel, grid, block, 0, stream,
                       x, emb_table, lin_w, lin_bias, codebooks, assignments,
                       arch, gumbel, out);
}

// Round 7
// 14.430 us; speedup vs baseline: 1.4282x; 1.4282x over previous
//
#include <hip/hip_runtime.h>

#define F 26
#define FPAD 32
#define A 7
#define DIM 16
#define BATCH 4096
#define TV 2083764

__device__ __constant__ int c_OFFSETS[F] = {
    0, 1000000, 1500000, 1750000, 1850000, 1950000, 2000000, 2050000,
    2060000, 2070000, 2075000, 2080000, 2081000, 2082000, 2082500, 2083000,
    2083200, 2083400, 2083500, 2083600, 2083650, 2083700, 2083720, 2083740,
    2083750, 2083760};
__device__ __constant__ int c_FIELD_DIMS[F] = {
    1000000, 500000, 250000, 100000, 100000, 50000, 50000, 10000, 10000,
    5000, 5000, 1000, 1000, 500, 500, 200, 200, 100, 100, 50, 50, 20, 20,
    10, 10, 4};
__device__ __constant__ int c_ACTION[A] = {1, 64, 128, 256, 512, 1024, 2048};

// Block: 256 threads = 4 waves; ONE wave per batch element.
// Wave layout: lane = sub*4 + dh; sub = lane>>2 (0..15) owns fields
// f = sub + 16*j (j = 0,1); dh = lane&3 covers dims 4*dh..4*dh+3 (float4).
// ALL loads are unconditional with dead addresses clamped to offset 0
// (L1-resident) and weights exactly 0 -> no divergent branches, full hoisting.
__global__ __launch_bounds__(256, 4) void gsq_fm_kernel(
    const int* __restrict__ x,            // (B, F)
    const float* __restrict__ emb_table,  // (TV, 16)
    const float* __restrict__ lin_w,      // (TV, 1)
    const float* __restrict__ lin_bias,   // (1,)
    const float* __restrict__ codebooks,  // (6, F, 2048, 16)
    const int* __restrict__ assignments,  // (6, TV)
    const float* __restrict__ arch,       // (F, A)
    const float* __restrict__ gumbel,     // (F, A)
    float* __restrict__ out)              // (B,)
{
    __shared__ float probs_s[FPAD][A];
    __shared__ int gid_s[4][FPAD];

    const int t = threadIdx.x;

    // ---- stage gids for the block's 4 batch elements (threads 0..127) ----
    if (t < 128) {
        const int e = t >> 5;
        const int fi = t & 31;
        gid_s[e][fi] = (fi < F)
            ? (x[(blockIdx.x * 4 + e) * F + fi] + c_OFFSETS[fi])
            : 0;
    }

    // ---- per-block probs (threads 128..159; pad rows zero) ----
    if (t >= 128 && t < 128 + FPAD) {
        const int f = t - 128;
        if (f < F) {
            const int dims = c_FIELD_DIMS[f];
            float z[A];
            float m = -1e30f;
            for (int k = 0; k < A; ++k) {
                bool allowed = (k == 0) ? (dims < 150)
                                        : (5 * c_ACTION[k] <= 2 * dims);
                float logit = allowed ? arch[f * A + k] : -1e9f;
                z[k] = logit + gumbel[f * A + k];  // TEMPERATURE == 1
                m = fmaxf(m, z[k]);
            }
            float ssum = 0.f;
            for (int k = 0; k < A; ++k) {
                z[k] = expf(z[k] - m);  // disallowed -> exactly 0.0f
                ssum += z[k];
            }
            const float inv = 1.f / ssum;
            for (int k = 0; k < A; ++k) probs_s[f][k] = z[k] * inv;
        } else {
            for (int k = 0; k < A; ++k) probs_s[f][k] = 0.f;
        }
    }
    __syncthreads();

    const int lane = t & 63;
    const int e = t >> 6;          // wave id = batch sub-index (0..3)
    const int b = blockIdx.x * 4 + e;
    const int sub = lane >> 2;     // field sub-group 0..15
    const int dh = lane & 3;       // dims 4*dh .. 4*dh+3

    float sx = 0.f, sy = 0.f, sz = 0.f, sw = 0.f;  // sum_f xe[f, 4dh+0..3]
    float q = 0.f;     // sum_{f,d} xe^2 (this lane's share)
    float lin = 0.f;   // lin_w partial (dh==0 lanes only)

#pragma unroll
    for (int j = 0; j < 2; ++j) {
        const int f = sub + 16 * j;        // 0..31 (26..31 are dead pads)
        const int gid = gid_s[e][f];
        const bool valid = (f < F);

        // ---- emb path (clamped: dead lanes hit line 0, weight exactly 0) ----
        const float p0 = probs_s[f][0];
        const int eoff = (p0 != 0.f) ? gid * DIM : 0;
        const float4 er = *(const float4*)&emb_table[eoff + 4 * dh];
        float xx = p0 * er.x, xy = p0 * er.y, xz = p0 * er.z, xw = p0 * er.w;

        // ---- code gathers: unconditional, clamped, all independent ----
        float wgt[6];
        int coff[6];
#pragma unroll
        for (int a = 0; a < 6; ++a) {
            wgt[a] = probs_s[f][a + 1];          // exactly 0 for dead (f,a)
            const bool live = (wgt[a] != 0.f);
            const int aaddr = live ? (a * TV + gid) : 0;
            const int code = assignments[aaddr];
            coff[a] = live ? (((a * F + f) * 2048 + code) * DIM) : 0;
        }
        // ---- row gathers + accumulate (weights kill dead contributions) ----
#pragma unroll
        for (int a = 0; a < 6; ++a) {
            const float4 r = *(const float4*)&codebooks[coff[a] + 4 * dh];
            xx = fmaf(wgt[a], r.x, xx);
            xy = fmaf(wgt[a], r.y, xy);
            xz = fmaf(wgt[a], r.z, xz);
            xw = fmaf(wgt[a], r.w, xw);
        }

        sx += xx; sy += xy; sz += xz; sw += xw;
        q = fmaf(xx, xx, q);
        q = fmaf(xy, xy, q);
        q = fmaf(xz, xz, q);
        q = fmaf(xw, xw, q);

        // lin: branchless masked (all 4 dh lanes load the same line)
        const float lm = (dh == 0 && valid) ? 1.f : 0.f;
        const float lv = lin_w[valid ? gid : 0];
        lin = fmaf(lm, lv, lin);
    }

    // ---- in-wave reductions ----
    // s: sum across the 16 sub-groups (lane bits 2..5)
    sx += __shfl_xor(sx, 4, 64);  sx += __shfl_xor(sx, 8, 64);
    sx += __shfl_xor(sx, 16, 64); sx += __shfl_xor(sx, 32, 64);
    sy += __shfl_xor(sy, 4, 64);  sy += __shfl_xor(sy, 8, 64);
    sy += __shfl_xor(sy, 16, 64); sy += __shfl_xor(sy, 32, 64);
    sz += __shfl_xor(sz, 4, 64);  sz += __shfl_xor(sz, 8, 64);
    sz += __shfl_xor(sz, 16, 64); sz += __shfl_xor(sz, 32, 64);
    sw += __shfl_xor(sw, 4, 64);  sw += __shfl_xor(sw, 8, 64);
    sw += __shfl_xor(sw, 16, 64); sw += __shfl_xor(sw, 32, 64);

    // q, lin: full 64-lane butterflies
    q += __shfl_xor(q, 1, 64);  q += __shfl_xor(q, 2, 64);
    q += __shfl_xor(q, 4, 64);  q += __shfl_xor(q, 8, 64);
    q += __shfl_xor(q, 16, 64); q += __shfl_xor(q, 32, 64);
    lin += __shfl_xor(lin, 1, 64);  lin += __shfl_xor(lin, 2, 64);
    lin += __shfl_xor(lin, 4, 64);  lin += __shfl_xor(lin, 8, 64);
    lin += __shfl_xor(lin, 16, 64); lin += __shfl_xor(lin, 32, 64);

    // s^2 dot: per-lane partial over its 4 dims, then sum across dh (bits 0,1)
    float val = sx * sx + sy * sy + sz * sz + sw * sw;
    val += __shfl_xor(val, 1, 64);
    val += __shfl_xor(val, 2, 64);

    if (lane == 0) {
        out[b] = lin + lin_bias[0] + 0.5f * (val - q);
    }
}

extern "C" void kernel_launch(void* const* d_in, const int* in_sizes, int n_in,
                              void* d_out, int out_size, void* d_ws, size_t ws_size,
                              hipStream_t stream) {
    const int*   x           = (const int*)d_in[0];
    const float* emb_table   = (const float*)d_in[1];
    const float* lin_w       = (const float*)d_in[2];
    const float* lin_bias    = (const float*)d_in[3];
    const float* codebooks   = (const float*)d_in[4];
    const int*   assignments = (const int*)d_in[5];
    const float* arch        = (const float*)d_in[6];
    const float* gumbel      = (const float*)d_in[7];
    float* out = (float*)d_out;

    dim3 grid(BATCH / 4);   // 4 batch elements (1 wave each) per block
    dim3 block(256);
    hipLaunchKernelGGL(gsq_fm_kernel, grid, block, 0, stream,
                       x, emb_table, lin_w, lin_bias, codebooks, assignments,
                       arch, gumbel, out);
}

// Round 8
// 13.574 us; speedup vs baseline: 1.5183x; 1.0631x over previous
//
#include <hip/hip_runtime.h>

#define F 26
#define FPAD 32
#define A 7
#define DIM 16
#define BATCH 4096
#define TV 2083764

__device__ __constant__ int c_OFFSETS[F] = {
    0, 1000000, 1500000, 1750000, 1850000, 1950000, 2000000, 2050000,
    2060000, 2070000, 2075000, 2080000, 2081000, 2082000, 2082500, 2083000,
    2083200, 2083400, 2083500, 2083600, 2083650, 2083700, 2083720, 2083740,
    2083750, 2083760};
__device__ __constant__ int c_FIELD_DIMS[F] = {
    1000000, 500000, 250000, 100000, 100000, 50000, 50000, 10000, 10000,
    5000, 5000, 1000, 1000, 500, 500, 200, 200, 100, 100, 50, 50, 20, 20,
    10, 10, 4};
__device__ __constant__ int c_ACTION[A] = {1, 64, 128, 256, 512, 1024, 2048};

// Block: 256 threads = 4 waves = 2 batch elements (2 waves per element).
// Wave h of a pair handles fields f = h*16 + sub, sub = lane>>2 (0..15);
// dh = lane&3 covers dims 4*dh..4*dh+3 (float4). Branchless clamped loads
// (dead -> line 0, weight exactly 0), as proven in round 7.
__global__ __launch_bounds__(256, 8) void gsq_fm_kernel(
    const int* __restrict__ x,            // (B, F)
    const float* __restrict__ emb_table,  // (TV, 16)
    const float* __restrict__ lin_w,      // (TV, 1)
    const float* __restrict__ lin_bias,   // (1,)
    const float* __restrict__ codebooks,  // (6, F, 2048, 16)
    const int* __restrict__ assignments,  // (6, TV)
    const float* __restrict__ arch,       // (F, A)
    const float* __restrict__ gumbel,     // (F, A)
    float* __restrict__ out)              // (B,)
{
    __shared__ float probs_s[FPAD][A];
    __shared__ int gid_s[2][FPAD];
    __shared__ float4 s_red[2][2][4];   // [e][h][dh]
    __shared__ float q_red[2][2];
    __shared__ float lin_red[2][2];

    const int t = threadIdx.x;

    // ---- stage gids for the block's 2 batch elements (threads 0..63) ----
    if (t < 64) {
        const int e = t >> 5;
        const int fi = t & 31;
        gid_s[e][fi] = (fi < F)
            ? (x[(blockIdx.x * 2 + e) * F + fi] + c_OFFSETS[fi])
            : 0;
    }

    // ---- per-block probs (threads 64..95; pad rows zero) ----
    if (t >= 64 && t < 64 + FPAD) {
        const int f = t - 64;
        if (f < F) {
            const int dims = c_FIELD_DIMS[f];
            float z[A];
            float m = -1e30f;
            for (int k = 0; k < A; ++k) {
                bool allowed = (k == 0) ? (dims < 150)
                                        : (5 * c_ACTION[k] <= 2 * dims);
                float logit = allowed ? arch[f * A + k] : -1e9f;
                z[k] = logit + gumbel[f * A + k];  // TEMPERATURE == 1
                m = fmaxf(m, z[k]);
            }
            float ssum = 0.f;
            for (int k = 0; k < A; ++k) {
                z[k] = expf(z[k] - m);  // disallowed -> exactly 0.0f
                ssum += z[k];
            }
            const float inv = 1.f / ssum;
            for (int k = 0; k < A; ++k) probs_s[f][k] = z[k] * inv;
        } else {
            for (int k = 0; k < A; ++k) probs_s[f][k] = 0.f;
        }
    }
    __syncthreads();

    const int lane = t & 63;
    const int h = (t >> 6) & 1;    // wave within pair
    const int e = t >> 7;          // batch sub-index (0..1)
    const int b = blockIdx.x * 2 + e;
    const int sub = lane >> 2;     // field sub-group 0..15
    const int dh = lane & 3;       // dims 4*dh .. 4*dh+3

    const int f = h * 16 + sub;    // 0..31 (26..31 dead pads in wave h=1)
    const int gid = gid_s[e][f];
    const bool valid = (f < F);

    // ---- emb path (clamped: dead -> line 0, weight exactly 0) ----
    const float p0 = probs_s[f][0];
    const int eoff = (p0 != 0.f) ? gid * DIM : 0;
    const float4 er = *(const float4*)&emb_table[eoff + 4 * dh];
    float xx = p0 * er.x, xy = p0 * er.y, xz = p0 * er.z, xw = p0 * er.w;

    // ---- code gathers: unconditional, clamped, all independent ----
    float wgt[6];
    int coff[6];
#pragma unroll
    for (int a = 0; a < 6; ++a) {
        wgt[a] = probs_s[f][a + 1];          // exactly 0 for dead (f,a)
        const bool live = (wgt[a] != 0.f);
        const int aaddr = live ? (a * TV + gid) : 0;
        const int code = assignments[aaddr];
        coff[a] = live ? (((a * F + f) * 2048 + code) * DIM) : 0;
    }
    // ---- row gathers + accumulate ----
#pragma unroll
    for (int a = 0; a < 6; ++a) {
        const float4 r = *(const float4*)&codebooks[coff[a] + 4 * dh];
        xx = fmaf(wgt[a], r.x, xx);
        xy = fmaf(wgt[a], r.y, xy);
        xz = fmaf(wgt[a], r.z, xz);
        xw = fmaf(wgt[a], r.w, xw);
    }

    float q = xx * xx + xy * xy + xz * xz + xw * xw;

    // lin: branchless masked
    const float lm = (dh == 0 && valid) ? 1.f : 0.f;
    const float lv = lin_w[valid ? gid : 0];
    float lin = lm * lv;

    // ---- in-wave reductions ----
    float sx = xx, sy = xy, sz = xz, sw = xw;
    // s: sum across the 16 sub-groups (lane bits 2..5)
    sx += __shfl_xor(sx, 4, 64);  sx += __shfl_xor(sx, 8, 64);
    sx += __shfl_xor(sx, 16, 64); sx += __shfl_xor(sx, 32, 64);
    sy += __shfl_xor(sy, 4, 64);  sy += __shfl_xor(sy, 8, 64);
    sy += __shfl_xor(sy, 16, 64); sy += __shfl_xor(sy, 32, 64);
    sz += __shfl_xor(sz, 4, 64);  sz += __shfl_xor(sz, 8, 64);
    sz += __shfl_xor(sz, 16, 64); sz += __shfl_xor(sz, 32, 64);
    sw += __shfl_xor(sw, 4, 64);  sw += __shfl_xor(sw, 8, 64);
    sw += __shfl_xor(sw, 16, 64); sw += __shfl_xor(sw, 32, 64);

    // q, lin: full 64-lane butterflies
    q += __shfl_xor(q, 1, 64);  q += __shfl_xor(q, 2, 64);
    q += __shfl_xor(q, 4, 64);  q += __shfl_xor(q, 8, 64);
    q += __shfl_xor(q, 16, 64); q += __shfl_xor(q, 32, 64);
    lin += __shfl_xor(lin, 1, 64);  lin += __shfl_xor(lin, 2, 64);
    lin += __shfl_xor(lin, 4, 64);  lin += __shfl_xor(lin, 8, 64);
    lin += __shfl_xor(lin, 16, 64); lin += __shfl_xor(lin, 32, 64);

    if (lane < 4) {
        s_red[e][h][lane] = make_float4(sx, sy, sz, sw);
    }
    if (lane == 0) {
        q_red[e][h] = q;
        lin_red[e][h] = lin;
    }
    __syncthreads();

    // ---- cross-wave combine (wave h==0 of each pair) ----
    if (h == 0) {
        const float4 a0 = s_red[e][0][dh];
        const float4 a1 = s_red[e][1][dh];
        const float tx = a0.x + a1.x, ty = a0.y + a1.y;
        const float tz = a0.z + a1.z, tw = a0.w + a1.w;
        float val = tx * tx + ty * ty + tz * tz + tw * tw;  // per-dh partial
        val += __shfl_xor(val, 1, 64);
        val += __shfl_xor(val, 2, 64);
        if (lane == 0) {
            const float qt = q_red[e][0] + q_red[e][1];
            const float lt = lin_red[e][0] + lin_red[e][1];
            out[b] = lt + lin_bias[0] + 0.5f * (val - qt);
        }
    }
}

extern "C" void kernel_launch(void* const* d_in, const int* in_sizes, int n_in,
                              void* d_out, int out_size, void* d_ws, size_t ws_size,
                              hipStream_t stream) {
    const int*   x           = (const int*)d_in[0];
    const float* emb_table   = (const float*)d_in[1];
    const float* lin_w       = (const float*)d_in[2];
    const float* lin_bias    = (const float*)d_in[3];
    const float* codebooks   = (const float*)d_in[4];
    const int*   assignments = (const int*)d_in[5];
    const float* arch        = (const float*)d_in[6];
    const float* gumbel      = (const float*)d_in[7];
    float* out = (float*)d_out;

    dim3 grid(BATCH / 2);   // 2 batch elements (2 waves each) per block
    dim3 block(256);
    hipLaunchKernelGGL(gsq_fm_kernel, grid, block, 0, stream,
                       x, emb_table, lin_w, lin_bias, codebooks, assignments,
                       arch, gumbel, out);
}